// Round 1
// baseline (268.966 us; speedup 1.0000x reference)
//
#include <hip/hip_runtime.h>

#define N_EDGES 800000
#define N_NODES 50000
#define D 64                 // D_FEAT == EDGE_DIM == 64, K = 2*D = 128

typedef __attribute__((ext_vector_type(8))) short bf16x8;  // 8 bf16 = 16 B
typedef __attribute__((ext_vector_type(4))) float f32x4;   // MFMA accumulator

#if __has_builtin(__builtin_amdgcn_exp2f)
#define EXP2F(x) __builtin_amdgcn_exp2f(x)
#else
#define EXP2F(x) __expf(0.69314718055994531f * (x))
#endif

// f32 -> bf16 round-to-nearest-even (finite inputs)
__device__ __forceinline__ unsigned short f2bf(float f) {
    unsigned int u = __float_as_uint(f);
    u += 0x7fffu + ((u >> 16) & 1u);
    return (unsigned short)(u >> 16);
}
__device__ __forceinline__ unsigned int pack2(float a, float b) {
    return (unsigned int)f2bf(a) | ((unsigned int)f2bf(b) << 16);
}

// Prep (runs every call; ws re-poisoned each iter):
//  (a) node_feats (50000x64 f32) -> bf16 table (6.4 MB)
//  (b) W (128x64 f32) -> per-lane MFMA fragment order: 1024 x 16B entries.
//      entry idx = (ki*4+nt)*64 + l, l = q*16+m:
//      frag[j] = bf16(W[ki*32+q*8+j][nt*16+m]), j=0..7
//      (A/B fragment layouts are symmetric, so the same entries serve as the
//       A-operand W^T fragments after the operand swap below.)
__global__ __launch_bounds__(256) void prep(
    const float* __restrict__ nf, const float* __restrict__ W,
    unsigned short* __restrict__ nodes_bf, unsigned short* __restrict__ wfrag)
{
    if (blockIdx.x == gridDim.x - 1) {
#pragma unroll
        for (int i = 0; i < 4; ++i) {
            const int idx = i * 256 + threadIdx.x;     // 0..1023
            const int ki = idx >> 8;
            const int nt = (idx >> 6) & 3;
            const int l  = idx & 63;
            const int m  = l & 15, q = l >> 4;
            const int kbase = ki * 32 + q * 8;
            const int n = nt * 16 + m;
            unsigned short* dst = wfrag + idx * 8;
#pragma unroll
            for (int j = 0; j < 8; ++j)
                dst[j] = f2bf(W[(kbase + j) * D + n]);
        }
    } else {
        const long base = ((long)blockIdx.x * 256 + threadIdx.x) * 8;
        if (base < (long)N_NODES * D) {
            const float4 lo = *(const float4*)(nf + base);
            const float4 hi = *(const float4*)(nf + base + 4);
            uint4 p;
            p.x = pack2(lo.x, lo.y);
            p.y = pack2(lo.z, lo.w);
            p.z = pack2(hi.x, hi.y);
            p.w = pack2(hi.z, hi.w);
            *(uint4*)(nodes_bf + base) = p;
        }
    }
}

// One wave = 64 edges (4 m-tiles of 16). Block = 4 waves = 256 edges.
// Operand-swapped MFMA: D' = (W-slice)^T · feats^T, so
//   acc[mt][nt][r] = pre-activation for edge (e0+mt*16+m), feature (nt*16+q*4+r)
// => each lane owns 4 CONTIGUOUS output features -> dwordx4 stores.
__global__ __launch_bounds__(256) void edge_mlp(
    const unsigned short* __restrict__ nodes_bf,  // [N_NODES][64] bf16
    const bf16x8*        __restrict__ wfrag,      // [1024] fragments, 16 KB
    const int*   __restrict__ senders,
    const int*   __restrict__ receivers,
    const float* __restrict__ bias,
    float*       __restrict__ out)                // [N_EDGES][64] f32
{
    __shared__ bf16x8 lds_b[1024];                // 16 KB, fragment order

    // Stage W-fragments: 4 fully-coalesced 16B/lane loads, lane-contiguous
    // ds_write/ds_read (2-way aliasing only -> conflict-free on gfx950).
#pragma unroll
    for (int i = 0; i < 4; ++i) {
        const int idx = i * 256 + threadIdx.x;
        lds_b[idx] = wfrag[idx];
    }
    __syncthreads();

    const int lane = threadIdx.x & 63;
    const int m    = lane & 15;   // edge-within-tile (D' col)
    const int q    = lane >> 4;   // quad: k-slice owner / feature group
    const long wid = (long)blockIdx.x * 4 + (threadIdx.x >> 6);
    const long e0  = wid * 64;    // grid is exact: 800000/64 waves

    // Indices: 2 lane-contiguous loads + shuffle distribution
    const int rv = receivers[e0 + lane];
    const int sv = senders[e0 + lane];
    int nidx[2][4];
#pragma unroll
    for (int mt = 0; mt < 4; ++mt) {
        nidx[0][mt] = __shfl(rv, mt * 16 + m, 64);
        nidx[1][mt] = __shfl(sv, mt * 16 + m, 64);
    }

    f32x4 acc[4][4];
#pragma unroll
    for (int mt = 0; mt < 4; ++mt)
#pragma unroll
        for (int nt = 0; nt < 4; ++nt)
            acc[mt][nt] = (f32x4)0.0f;

#pragma unroll
    for (int ki = 0; ki < 4; ++ki) {           // K = 128 in 4 slices of 32
        const int k0 = ki * 32 + q * 8;

        // W fragments from LDS (pre-swizzled, lane-contiguous)
        bf16x8 bfrag[4];
#pragma unroll
        for (int nt = 0; nt < 4; ++nt)
            bfrag[nt] = lds_b[(ki * 4 + nt) * 64 + lane];

        // feats fragments: one 16B gather per mt from the bf16 node row
        bf16x8 afrag[4];
#pragma unroll
        for (int mt = 0; mt < 4; ++mt) {
            const int node = nidx[ki >> 1][mt];   // ki 0,1 -> recv; 2,3 -> send
            afrag[mt] = *(const bf16x8*)(nodes_bf + node * D + (k0 & 63));
        }

        // OPERAND SWAP: A = W^T fragment, B = feats fragment.
        // A/B lane layouts are symmetric, so the same bytes are valid;
        // output tile comes out transposed (feature-major per lane).
#pragma unroll
        for (int mt = 0; mt < 4; ++mt)
#pragma unroll
            for (int nt = 0; nt < 4; ++nt)
                acc[mt][nt] = __builtin_amdgcn_mfma_f32_16x16x32_bf16(
                    bfrag[nt], afrag[mt], acc[mt][nt], 0, 0, 0);
    }

    // Epilogue: lane (q,m) holds features nt*16+q*4 .. +3 of edge e0+mt*16+m.
    // tanh(x) = 1 - 2/(exp2(C*x + C*b) + 1), C = 2*log2(e); bias folded in.
    const float C2L = 2.8853900817779268f;    // 2*log2(e)
    f32x4 cb[4];
#pragma unroll
    for (int nt = 0; nt < 4; ++nt) {
        const float4 b4 = *(const float4*)(bias + nt * 16 + q * 4);
        cb[nt] = (f32x4){b4.x * C2L, b4.y * C2L, b4.z * C2L, b4.w * C2L};
    }

#pragma unroll
    for (int mt = 0; mt < 4; ++mt) {
        float* op = out + (e0 + mt * 16 + m) * D + q * 4;
#pragma unroll
        for (int nt = 0; nt < 4; ++nt) {
            f32x4 y;
#pragma unroll
            for (int r = 0; r < 4; ++r) {
                const float t  = EXP2F(__builtin_fmaf(acc[mt][nt][r], C2L, cb[nt][r]));
                const float rc = __builtin_amdgcn_rcpf(t + 1.0f);
                y[r] = __builtin_fmaf(-2.0f, rc, 1.0f);   // saturates to +/-1
            }
            __builtin_nontemporal_store(y, (f32x4*)(op + nt * 16));
        }
    }
}

extern "C" void kernel_launch(void* const* d_in, const int* in_sizes, int n_in,
                              void* d_out, int out_size, void* d_ws, size_t ws_size,
                              hipStream_t stream) {
    const float* node_feats = (const float*)d_in[0];
    const int*   senders    = (const int*)d_in[1];
    const int*   receivers  = (const int*)d_in[2];
    const float* W          = (const float*)d_in[3];
    const float* bias       = (const float*)d_in[4];
    float*       out        = (float*)d_out;

    // ws layout: [0, 6.4MB) bf16 node table (16B-aligned); then wfrag 16 KB
    unsigned short* nodes_bf = (unsigned short*)d_ws;
    unsigned short* wfrag    = (unsigned short*)((char*)d_ws + (size_t)N_NODES * D * 2);

    const int node_blocks = ((N_NODES * D / 8) + 255) / 256;   // 1563
    prep<<<node_blocks + 1, 256, 0, stream>>>(node_feats, W, nodes_bf, wfrag);

    const int n_blocks = N_EDGES / 256;   // 3125 exact: 4 waves/block, 64 edges/wave
    edge_mlp<<<n_blocks, 256, 0, stream>>>(nodes_bf, (const bf16x8*)wfrag,
                                           senders, receivers, bias, out);
}